// Round 2
// baseline (716.112 us; speedup 1.0000x reference)
//
#include <hip/hip_runtime.h>
#include <math.h>

typedef __bf16 bf16;
typedef short  s16x8  __attribute__((ext_vector_type(8)));  // MFMA A/B frag (8 bf16 bits)
typedef __bf16 bf16x4 __attribute__((ext_vector_type(4)));
typedef __bf16 bf16x2 __attribute__((ext_vector_type(2)));
typedef float  f32x4  __attribute__((ext_vector_type(4)));

constexpr int CB = 2, CS = 4096, CD = 2048, CHQ = 16, CHKV = 4, CHD = 128, CW = 512;
constexpr int CM = CB * CS;   // 8192 rows

#define MFMA16(a, b, c) __builtin_amdgcn_mfma_f32_16x16x32_bf16((a), (b), (c), 0, 0, 0)

// ---------------------------------------------------------------- RMSNorm ---
__global__ __launch_bounds__(256) void k_rmsnorm(const float* __restrict__ x,
                                                 const float* __restrict__ g,
                                                 bf16* __restrict__ xn) {
  const int row = blockIdx.x;
  const int tid = threadIdx.x;
  const float* xr = x + (size_t)row * CD;
  float4 v0 = *(const float4*)(xr + tid * 4);
  float4 v1 = *(const float4*)(xr + tid * 4 + 1024);
  float ss = v0.x * v0.x + v0.y * v0.y + v0.z * v0.z + v0.w * v0.w
           + v1.x * v1.x + v1.y * v1.y + v1.z * v1.z + v1.w * v1.w;
#pragma unroll
  for (int o = 1; o < 64; o <<= 1) ss += __shfl_xor(ss, o);
  __shared__ float red[4];
  if ((tid & 63) == 0) red[tid >> 6] = ss;
  __syncthreads();
  float tot = red[0] + red[1] + red[2] + red[3];
  float inv = rsqrtf(tot * (1.0f / CD) + 1e-6f);
  float4 g0 = *(const float4*)(g + tid * 4);
  float4 g1 = *(const float4*)(g + tid * 4 + 1024);
  bf16x4 o0, o1;
  o0[0] = (bf16)(v0.x * inv * g0.x); o0[1] = (bf16)(v0.y * inv * g0.y);
  o0[2] = (bf16)(v0.z * inv * g0.z); o0[3] = (bf16)(v0.w * inv * g0.w);
  o1[0] = (bf16)(v1.x * inv * g1.x); o1[1] = (bf16)(v1.y * inv * g1.y);
  o1[2] = (bf16)(v1.z * inv * g1.z); o1[3] = (bf16)(v1.w * inv * g1.w);
  *(bf16x4*)(xn + (size_t)row * CD + tid * 4) = o0;
  *(bf16x4*)(xn + (size_t)row * CD + tid * 4 + 1024) = o1;
}

// ------------------------------------------- weight transpose fp32 -> bf16 ---
// Wsrc[K][N] -> Wt[N][K]
__global__ __launch_bounds__(256) void k_transpose(const float* __restrict__ Wsrc,
                                                   bf16* __restrict__ Wt,
                                                   int K, int N) {
  __shared__ float tile[32][33];
  const int tx = threadIdx.x & 31, ty = threadIdx.x >> 5;  // ty 0..7
  const int c0 = blockIdx.x * 32, r0 = blockIdx.y * 32;
#pragma unroll
  for (int i = 0; i < 32; i += 8)
    tile[ty + i][tx] = Wsrc[(size_t)(r0 + ty + i) * N + c0 + tx];
  __syncthreads();
#pragma unroll
  for (int i = 0; i < 32; i += 8)
    Wt[(size_t)(c0 + ty + i) * K + r0 + tx] = (bf16)tile[tx][ty + i];
}

// ------------------------------------------------------------- RoPE tables ---
__global__ __launch_bounds__(256) void k_rope_tables(float* __restrict__ cosT,
                                                     float* __restrict__ sinT) {
  int idx = blockIdx.x * 256 + threadIdx.x;  // S*64
  int s = idx >> 6, i = idx & 63;
  double f = (double)s * pow(10000.0, -(double)i / 64.0);
  cosT[idx] = (float)cos(f);
  sinT[idx] = (float)sin(f);
}

// ------------------------------------------------------ RoPE apply in-place ---
// layout [b][s][nh][64 pairs]; flat pair idx enumerates exactly that order.
__global__ __launch_bounds__(256) void k_rope(bf16* __restrict__ qk,
                                              const float* __restrict__ cosT,
                                              const float* __restrict__ sinT,
                                              int lognh) {
  size_t idx = (size_t)blockIdx.x * 256 + threadIdx.x;
  int i = (int)(idx & 63);
  int s = (int)((idx >> (6 + lognh)) & (CS - 1));
  bf16x2 p = *(bf16x2*)(qk + 2 * idx);
  float xe = (float)p[0], xo = (float)p[1];
  float c = cosT[s * 64 + i], sn = sinT[s * 64 + i];
  bf16x2 o;
  o[0] = (bf16)(xe * c - xo * sn);
  o[1] = (bf16)(xe * sn + xo * c);
  *(bf16x2*)(qk + 2 * idx) = o;
}

// ------------------------------------------------------------------- GEMM ----
// C[M][N] = A[M][K] * W[K][N], with W given transposed: Bt[N][K]. bf16 in,
// fp32 accum. 128x128 tile, BK=64, 4 waves (2x2), 16x16x32 MFMA.
// EPI: 0 = fp32 natural, 1 = bf16 natural, 2 = bf16 V-transpose [b][kv][d][s]
constexpr int BM = 128, BN = 128, BK = 64;

template <int EPI>
__global__ __launch_bounds__(256)
void k_gemm(const bf16* __restrict__ A, const bf16* __restrict__ Bt,
            void* __restrict__ Cp, int M, int N, int K) {
  __shared__ alignas(16) bf16 As[BM * BK];
  __shared__ alignas(16) bf16 Bs[BN * BK];
  const int tid = threadIdx.x;
  const int wave = tid >> 6;
  const int lane = tid & 63;
  const int bn0 = blockIdx.x * BN;
  const int bm0 = blockIdx.y * BM;
  const int wm = wave >> 1, wn = wave & 1;

  // staging: 16 segments of 1KB per operand; thread's 16B lands at seg+lane*16
  // (global_load_lds writes LDS linearly: wave-uniform base + lane*16).
  // LDS[r][cb] holds global col byte (cb ^ ((r&7)<<4)) -- XOR involution,
  // applied on BOTH the source address and the LDS read (rule #21).
  int segBase[4], srcOff[4];
#pragma unroll
  for (int i = 0; i < 4; ++i) {
    int o = ((i * 4 + wave) << 10) + lane * 16;
    int r = o >> 7;                       // 128B per row (BK=64 bf16)
    int cb = (o & 127) ^ ((r & 7) << 4);
    segBase[i] = (i * 4 + wave) << 10;
    srcOff[i] = r * (K * 2) + cb;
  }
  const char* Abase = (const char*)A + (size_t)bm0 * (K * 2);
  const char* Bbase = (const char*)Bt + (size_t)bn0 * (K * 2);
  char* AsB = (char*)As;
  char* BsB = (char*)Bs;

  f32x4 acc[4][4];
#pragma unroll
  for (int i = 0; i < 4; ++i)
#pragma unroll
    for (int j = 0; j < 4; ++j) acc[i][j] = (f32x4){0.f, 0.f, 0.f, 0.f};

  const int nkt = K >> 6;
  for (int kt = 0; kt < nkt; ++kt) {
#pragma unroll
    for (int i = 0; i < 4; ++i)
      __builtin_amdgcn_global_load_lds(
          (const __attribute__((address_space(1))) void*)(Abase + srcOff[i] + kt * 128),
          (__attribute__((address_space(3))) void*)(AsB + segBase[i]), 16, 0, 0);
#pragma unroll
    for (int i = 0; i < 4; ++i)
      __builtin_amdgcn_global_load_lds(
          (const __attribute__((address_space(1))) void*)(Bbase + srcOff[i] + kt * 128),
          (__attribute__((address_space(3))) void*)(BsB + segBase[i]), 16, 0, 0);
    __syncthreads();  // compiler drains vmcnt before s_barrier
#pragma unroll
    for (int kk = 0; kk < 2; ++kk) {
      s16x8 af[4], bfv[4];
#pragma unroll
      for (int i = 0; i < 4; ++i) {
        int row = wm * 64 + i * 16 + (lane & 15);
        int cb = ((kk * 64) + ((lane >> 4) * 16)) ^ ((row & 7) << 4);
        af[i] = *(const s16x8*)(AsB + row * 128 + cb);
        int rowb = wn * 64 + i * 16 + (lane & 15);
        int cbb = ((kk * 64) + ((lane >> 4) * 16)) ^ ((rowb & 7) << 4);
        bfv[i] = *(const s16x8*)(BsB + rowb * 128 + cbb);
      }
#pragma unroll
      for (int i = 0; i < 4; ++i)
#pragma unroll
        for (int j = 0; j < 4; ++j)
          acc[i][j] = MFMA16(af[i], bfv[j], acc[i][j]);
    }
    __syncthreads();
  }

  // epilogue. C/D layout: col = lane&15, row = (lane>>4)*4 + reg  (m89/m91)
  const int lr = (lane >> 4) * 4;
  const int lc = lane & 15;
  if constexpr (EPI == 2) {
    bf16* C = (bf16*)Cp;
#pragma unroll
    for (int i = 0; i < 4; ++i)
#pragma unroll
      for (int j = 0; j < 4; ++j) {
        int n = bn0 + wn * 64 + j * 16 + lc;
        int kvh = n >> 7, d = n & 127;
        int m = bm0 + wm * 64 + i * 16 + lr;          // token; regs r = m+r
        int b = m >> 12, s0i = m & (CS - 1);
        bf16x4 pk;
        pk[0] = (bf16)acc[i][j][0]; pk[1] = (bf16)acc[i][j][1];
        pk[2] = (bf16)acc[i][j][2]; pk[3] = (bf16)acc[i][j][3];
        *(bf16x4*)(C + (((size_t)b * CHKV + kvh) * CHD + d) * CS + s0i) = pk;
      }
  } else {
#pragma unroll
    for (int i = 0; i < 4; ++i)
#pragma unroll
      for (int j = 0; j < 4; ++j) {
        int n = bn0 + wn * 64 + j * 16 + lc;
        int m = bm0 + wm * 64 + i * 16 + lr;
#pragma unroll
        for (int r = 0; r < 4; ++r) {
          if constexpr (EPI == 0)
            ((float*)Cp)[(size_t)(m + r) * N + n] = acc[i][j][r];
          else
            ((bf16*)Cp)[(size_t)(m + r) * N + n] = (bf16)acc[i][j][r];
        }
      }
  }
}

// -------------------------------------------------------------- attention ----
// Sliding window [q-512, q], GQA. Block = (b, kv, 16-query tile); 4 waves =
// the 4 q-heads sharing that kv head. Swapped QK^T (mfma(K,Q)) so softmax
// stats and O^T accumulator are indexed by q = lane&15. No LDS.
// Desk-proof: every 32-key chunk intersects every lane's window, so cm is
// finite after masking and the only -inf is the initial m_run (exp(-inf)=0).
__global__ __launch_bounds__(256) void k_attn(const bf16* __restrict__ Q,
                                              const bf16* __restrict__ Kb,
                                              const bf16* __restrict__ Vt,
                                              bf16* __restrict__ O) {
  const int blk = blockIdx.x;
  const int qt = blk & (CS / 16 - 1);          // 256 q-tiles
  const int kv = (blk >> 8) & (CHKV - 1);
  const int b = blk >> 10;
  const int lane = threadIdx.x & 63;
  const int wavei = threadIdx.x >> 6;
  const int h = kv * (CHQ / CHKV) + wavei;
  const int q0 = qt * 16;
  const int g = lane >> 4, qi = lane & 15;
  const int qglob = q0 + qi;

  // Q as B-frag: col=q=lane&15, k-elems d=(lane>>4)*8+j
  const bf16* qbase = Q + (((size_t)b * CS + qglob) * CHQ + h) * CHD + g * 8;
  s16x8 qf[4];
#pragma unroll
  for (int t = 0; t < 4; ++t) qf[t] = *(const s16x8*)(qbase + t * 32);

  f32x4 ot[8];
#pragma unroll
  for (int t = 0; t < 8; ++t) ot[t] = (f32x4){0.f, 0.f, 0.f, 0.f};
  float m_run = -__builtin_inff(), l_run = 0.f;

  int kstart = q0 - CW;
  if (kstart < 0) kstart = 0;
  kstart &= ~31;
  const int nc = (q0 + 16 - kstart + 31) >> 5;   // max key read <= S-1 (proof)

  const size_t krow = (size_t)CHKV * CHD;  // K: [b][s][kv][d]
  const bf16* kb0 = Kb + (((size_t)b * CS) * CHKV + kv) * CHD + g * 8;
  const bf16* vb0 = Vt + (((size_t)b * CHKV + kv) * CHD + qi) * (size_t)CS + g * 8;

  const float scale = 0.08838834764831845f;  // 1/sqrt(128)

  for (int c = 0; c < nc; ++c) {
    const int kc = kstart + c * 32;
    f32x4 s0 = (f32x4){0.f, 0.f, 0.f, 0.f}, s1 = (f32x4){0.f, 0.f, 0.f, 0.f};
    const bf16* kptr = kb0 + (size_t)(kc + qi) * krow;
#pragma unroll
    for (int t = 0; t < 4; ++t) {
      s16x8 k0 = *(const s16x8*)(kptr + t * 32);
      s16x8 k1 = *(const s16x8*)(kptr + 16 * krow + t * 32);
      s0 = MFMA16(k0, qf[t], s0);
      s1 = MFMA16(k1, qf[t], s1);
    }
    // mask + scale. scoresT frag: row(key) = g*4+r, col(q) = qi
    float p0[4], p1[4];
#pragma unroll
    for (int r = 0; r < 4; ++r) {
      int key0 = kc + g * 4 + r;
      int key1 = key0 + 16;
      float a = s0[r] * scale, bb = s1[r] * scale;
      p0[r] = (key0 <= qglob && key0 + CW >= qglob) ? a : -__builtin_inff();
      p1[r] = (key1 <= qglob && key1 + CW >= qglob) ? bb : -__builtin_inff();
    }
    float cm = fmaxf(fmaxf(fmaxf(p0[0], p0[1]), fmaxf(p0[2], p0[3])),
                     fmaxf(fmaxf(p1[0], p1[1]), fmaxf(p1[2], p1[3])));
    cm = fmaxf(cm, __shfl_xor(cm, 16));
    cm = fmaxf(cm, __shfl_xor(cm, 32));
    float m_new = fmaxf(m_run, cm);
    float fs = __expf(m_run - m_new);  // first chunk: exp(-inf)=0
    float rs = 0.f;
#pragma unroll
    for (int r = 0; r < 4; ++r) { p0[r] = __expf(p0[r] - m_new); rs += p0[r]; }
#pragma unroll
    for (int r = 0; r < 4; ++r) { p1[r] = __expf(p1[r] - m_new); rs += p1[r]; }
    rs += __shfl_xor(rs, 16);
    rs += __shfl_xor(rs, 32);
    l_run = l_run * fs + rs;
    m_run = m_new;
#pragma unroll
    for (int t = 0; t < 8; ++t) {
      ot[t][0] *= fs; ot[t][1] *= fs; ot[t][2] *= fs; ot[t][3] *= fs;
    }
    // P^T B-frag: lane needs keys ko=8g+j for q=qi. ko=16*hi + gp*4 + (j&3),
    // hi=(g>=2), gp=(2g+(j>>2))&3; source lane = qi + 16*gp.
    s16x8 pb;
#pragma unroll
    for (int j = 0; j < 8; ++j) {
      int gp = (2 * g + (j >> 2)) & 3;
      int src = qi + (gp << 4);
      float a0 = __shfl(p0[j & 3], src);
      float a1 = __shfl(p1[j & 3], src);
      pb[j] = __builtin_bit_cast(short, (bf16)((g < 2) ? a0 : a1));
    }
    // O^T += V^T * P^T ; V^T A-frag is 16B contiguous thanks to [b][kv][d][s]
    const bf16* vb = vb0 + kc;
#pragma unroll
    for (int t = 0; t < 8; ++t) {
      s16x8 vf = *(const s16x8*)(vb + (size_t)t * 16 * CS);
      ot[t] = MFMA16(vf, pb, ot[t]);
    }
  }

  float invl = 1.0f / l_run;
  bf16* ob = O + (((size_t)b * CS + qglob) * CHQ + h) * CHD;
#pragma unroll
  for (int t = 0; t < 8; ++t) {
    bf16x4 pk;
    pk[0] = (bf16)(ot[t][0] * invl);
    pk[1] = (bf16)(ot[t][1] * invl);
    pk[2] = (bf16)(ot[t][2] * invl);
    pk[3] = (bf16)(ot[t][3] * invl);
    *(bf16x4*)(ob + t * 16 + g * 4) = pk;
  }
}

// ------------------------------------------------------------------ launch ---
extern "C" void kernel_launch(void* const* d_in, const int* in_sizes, int n_in,
                              void* d_out, int out_size, void* d_ws, size_t ws_size,
                              hipStream_t stream) {
  const float* x = (const float*)d_in[0];
  const float* g = (const float*)d_in[1];
  const float* wq = (const float*)d_in[2];
  const float* wk = (const float*)d_in[3];
  const float* wv = (const float*)d_in[4];
  const float* wo = (const float*)d_in[5];
  float* out = (float*)d_out;

  char* p = (char*)d_ws;
  bf16* xn = (bf16*)p;  p += (size_t)CM * CD * 2;          // 32 MiB
  bf16* wqT = (bf16*)p; p += (size_t)CD * CD * 2;          //  8 MiB
  bf16* wkT = (bf16*)p; p += (size_t)(CHKV * CHD) * CD * 2;//  2 MiB
  bf16* wvT = (bf16*)p; p += (size_t)(CHKV * CHD) * CD * 2;//  2 MiB
  bf16* woT = (bf16*)p; p += (size_t)CD * CD * 2;          //  8 MiB
  float* cosT = (float*)p; p += (size_t)CS * 64 * 4;       //  1 MiB
  float* sinT = (float*)p; p += (size_t)CS * 64 * 4;       //  1 MiB
  bf16* qb = (bf16*)p;  p += (size_t)CM * CD * 2;          // 32 MiB
  bf16* kb = (bf16*)p;  p += (size_t)CM * (CHKV * CHD) * 2;//  8 MiB
  bf16* vT = (bf16*)p;  p += (size_t)CM * (CHKV * CHD) * 2;//  8 MiB
  bf16* ao = xn;  // alias: xn is dead once the V projection GEMM has run
                  // (attention output buffer; consumed only by final GEMM)

  k_rope_tables<<<(CS * 64) / 256, 256, 0, stream>>>(cosT, sinT);
  k_rmsnorm<<<CM, 256, 0, stream>>>(x, g, xn);
  k_transpose<<<dim3(CD / 32, CD / 32), 256, 0, stream>>>(wq, wqT, CD, CD);
  k_transpose<<<dim3((CHKV * CHD) / 32, CD / 32), 256, 0, stream>>>(wk, wkT, CD, CHKV * CHD);
  k_transpose<<<dim3((CHKV * CHD) / 32, CD / 32), 256, 0, stream>>>(wv, wvT, CD, CHKV * CHD);
  k_transpose<<<dim3(CD / 32, CD / 32), 256, 0, stream>>>(wo, woT, CD, CD);

  k_gemm<1><<<dim3(CD / BN, CM / BM), 256, 0, stream>>>(xn, wqT, qb, CM, CD, CD);
  k_gemm<1><<<dim3((CHKV * CHD) / BN, CM / BM), 256, 0, stream>>>(xn, wkT, kb, CM, CHKV * CHD, CD);
  k_gemm<2><<<dim3((CHKV * CHD) / BN, CM / BM), 256, 0, stream>>>(xn, wvT, vT, CM, CHKV * CHD, CD);

  k_rope<<<(CM * CHQ * 64) / 256, 256, 0, stream>>>(qb, cosT, sinT, 4);   // NH=16
  k_rope<<<(CM * CHKV * 64) / 256, 256, 0, stream>>>(kb, cosT, sinT, 2);  // NH=4

  k_attn<<<CB * CHKV * (CS / 16), 256, 0, stream>>>(qb, kb, vT, ao);

  k_gemm<0><<<dim3(CD / BN, CM / BM), 256, 0, stream>>>(ao, woT, out, CM, CD, CD);
}

// Round 4
// 538.138 us; speedup vs baseline: 1.3307x; 1.3307x over previous
//
#include <hip/hip_runtime.h>
#include <math.h>

typedef __bf16 bf16;
typedef short  s16x8  __attribute__((ext_vector_type(8)));  // MFMA A/B frag (8 bf16)
typedef short  s16x4  __attribute__((ext_vector_type(4)));  // MFMA A/B frag (4 bf16)
typedef __bf16 bf16x4 __attribute__((ext_vector_type(4)));
typedef __bf16 bf16x2 __attribute__((ext_vector_type(2)));
typedef float  f32x4  __attribute__((ext_vector_type(4)));

constexpr int CB = 2, CS = 4096, CD = 2048, CHQ = 16, CHKV = 4, CHD = 128, CW = 512;
constexpr int CM = CB * CS;   // 8192 rows

#define MFMA32(a, b, c) __builtin_amdgcn_mfma_f32_16x16x32_bf16((a), (b), (c), 0, 0, 0)

#if defined(__has_builtin)
#if __has_builtin(__builtin_amdgcn_mfma_f32_16x16x16bf16_1k)
#define HAVE_MFMA16_1K 1
#endif
#endif

static __device__ __forceinline__ f32x4 MFMA16(s16x4 a, s16x4 b, f32x4 c) {
#ifdef HAVE_MFMA16_1K
  return __builtin_amdgcn_mfma_f32_16x16x16bf16_1k(a, b, c, 0, 0, 0);
#else
  asm volatile("v_mfma_f32_16x16x16_bf16 %0, %1, %2, %0" : "+v"(c) : "v"(a), "v"(b));
  return c;
#endif
}

// ---------------------------------------------------------------- RMSNorm ---
__global__ __launch_bounds__(256) void k_rmsnorm(const float* __restrict__ x,
                                                 const float* __restrict__ g,
                                                 bf16* __restrict__ xn) {
  const int row = blockIdx.x;
  const int tid = threadIdx.x;
  const float* xr = x + (size_t)row * CD;
  float4 v0 = *(const float4*)(xr + tid * 4);
  float4 v1 = *(const float4*)(xr + tid * 4 + 1024);
  float ss = v0.x * v0.x + v0.y * v0.y + v0.z * v0.z + v0.w * v0.w
           + v1.x * v1.x + v1.y * v1.y + v1.z * v1.z + v1.w * v1.w;
#pragma unroll
  for (int o = 1; o < 64; o <<= 1) ss += __shfl_xor(ss, o);
  __shared__ float red[4];
  if ((tid & 63) == 0) red[tid >> 6] = ss;
  __syncthreads();
  float tot = red[0] + red[1] + red[2] + red[3];
  float inv = rsqrtf(tot * (1.0f / CD) + 1e-6f);
  float4 g0 = *(const float4*)(g + tid * 4);
  float4 g1 = *(const float4*)(g + tid * 4 + 1024);
  bf16x4 o0, o1;
  o0[0] = (bf16)(v0.x * inv * g0.x); o0[1] = (bf16)(v0.y * inv * g0.y);
  o0[2] = (bf16)(v0.z * inv * g0.z); o0[3] = (bf16)(v0.w * inv * g0.w);
  o1[0] = (bf16)(v1.x * inv * g1.x); o1[1] = (bf16)(v1.y * inv * g1.y);
  o1[2] = (bf16)(v1.z * inv * g1.z); o1[3] = (bf16)(v1.w * inv * g1.w);
  *(bf16x4*)(xn + (size_t)row * CD + tid * 4) = o0;
  *(bf16x4*)(xn + (size_t)row * CD + tid * 4 + 1024) = o1;
}

// ------------------------------------------- weight transpose fp32 -> bf16 ---
__global__ __launch_bounds__(256) void k_transpose(const float* __restrict__ Wsrc,
                                                   bf16* __restrict__ Wt,
                                                   int K, int N) {
  __shared__ float tile[32][33];
  const int tx = threadIdx.x & 31, ty = threadIdx.x >> 5;
  const int c0 = blockIdx.x * 32, r0 = blockIdx.y * 32;
#pragma unroll
  for (int i = 0; i < 32; i += 8)
    tile[ty + i][tx] = Wsrc[(size_t)(r0 + ty + i) * N + c0 + tx];
  __syncthreads();
#pragma unroll
  for (int i = 0; i < 32; i += 8)
    Wt[(size_t)(c0 + ty + i) * K + r0 + tx] = (bf16)tile[tx][ty + i];
}

// ------------------------------------------------------------- RoPE tables ---
// fp64 pow only 64x (one tiny kernel); table kernel uses fp64 mul + range
// reduction + fast f32 sincos (error ~1e-7 rad, far below bf16 grain).
__global__ void k_rope_inv(double* __restrict__ inv) {
  int i = threadIdx.x;
  if (i < 64) inv[i] = pow(10000.0, -(double)i / 64.0);
}

__global__ __launch_bounds__(256) void k_rope_tables(const double* __restrict__ inv,
                                                     float* __restrict__ cosT,
                                                     float* __restrict__ sinT) {
  int idx = blockIdx.x * 256 + threadIdx.x;  // S*64
  int s = idx >> 6, i = idx & 63;
  double f = (double)s * inv[i];
  double n = floor(f * 0.15915494309189535 + 0.5);
  float r = (float)(f - n * 6.283185307179586);
  cosT[idx] = cosf(r);
  sinT[idx] = sinf(r);
}

// ------------------------------------------------------ RoPE apply in-place ---
// layout [...][s][nh][64 pairs] with s at bit offset (6+lognh). lognh=0 for
// the K layout [b][kv][s][64 pairs].
__global__ __launch_bounds__(256) void k_rope(bf16* __restrict__ qk,
                                              const float* __restrict__ cosT,
                                              const float* __restrict__ sinT,
                                              int lognh) {
  size_t idx = (size_t)blockIdx.x * 256 + threadIdx.x;
  int i = (int)(idx & 63);
  int s = (int)((idx >> (6 + lognh)) & (CS - 1));
  bf16x2 p = *(bf16x2*)(qk + 2 * idx);
  float xe = (float)p[0], xo = (float)p[1];
  float c = cosT[s * 64 + i], sn = sinT[s * 64 + i];
  bf16x2 o;
  o[0] = (bf16)(xe * c - xo * sn);
  o[1] = (bf16)(xe * sn + xo * c);
  *(bf16x2*)(qk + 2 * idx) = o;
}

// ------------------------------------------------------------------- GEMM ----
// C[M][N] = A[M][K] * Bt[N][K]^T. 128x128 tile, BK=64, 4 waves, 16x16x32 MFMA.
// EPI: 0 fp32 natural, 1 bf16 natural, 2 bf16 V^T [b][kv][d][s],
//      3 bf16 K-layout [b][kv][s][d]
constexpr int BM = 128, BN = 128, BK = 64;

template <int EPI>
__global__ __launch_bounds__(256)
void k_gemm(const bf16* __restrict__ A, const bf16* __restrict__ Bt,
            void* __restrict__ Cp, int M, int N, int K) {
  __shared__ alignas(16) bf16 As[BM * BK];
  __shared__ alignas(16) bf16 Bs[BN * BK];
  const int tid = threadIdx.x;
  const int wave = tid >> 6;
  const int lane = tid & 63;
  const int bn0 = blockIdx.x * BN;
  const int bm0 = blockIdx.y * BM;
  const int wm = wave >> 1, wn = wave & 1;

  int segBase[4], srcOff[4];
#pragma unroll
  for (int i = 0; i < 4; ++i) {
    int o = ((i * 4 + wave) << 10) + lane * 16;
    int r = o >> 7;
    int cb = (o & 127) ^ ((r & 7) << 4);
    segBase[i] = (i * 4 + wave) << 10;
    srcOff[i] = r * (K * 2) + cb;
  }
  const char* Abase = (const char*)A + (size_t)bm0 * (K * 2);
  const char* Bbase = (const char*)Bt + (size_t)bn0 * (K * 2);
  char* AsB = (char*)As;
  char* BsB = (char*)Bs;

  f32x4 acc[4][4];
#pragma unroll
  for (int i = 0; i < 4; ++i)
#pragma unroll
    for (int j = 0; j < 4; ++j) acc[i][j] = (f32x4){0.f, 0.f, 0.f, 0.f};

  const int nkt = K >> 6;
  for (int kt = 0; kt < nkt; ++kt) {
#pragma unroll
    for (int i = 0; i < 4; ++i)
      __builtin_amdgcn_global_load_lds(
          (const __attribute__((address_space(1))) void*)(Abase + srcOff[i] + kt * 128),
          (__attribute__((address_space(3))) void*)(AsB + segBase[i]), 16, 0, 0);
#pragma unroll
    for (int i = 0; i < 4; ++i)
      __builtin_amdgcn_global_load_lds(
          (const __attribute__((address_space(1))) void*)(Bbase + srcOff[i] + kt * 128),
          (__attribute__((address_space(3))) void*)(BsB + segBase[i]), 16, 0, 0);
    __syncthreads();
#pragma unroll
    for (int kk = 0; kk < 2; ++kk) {
      s16x8 af[4], bfv[4];
#pragma unroll
      for (int i = 0; i < 4; ++i) {
        int row = wm * 64 + i * 16 + (lane & 15);
        int cb = ((kk * 64) + ((lane >> 4) * 16)) ^ ((row & 7) << 4);
        af[i] = *(const s16x8*)(AsB + row * 128 + cb);
        int rowb = wn * 64 + i * 16 + (lane & 15);
        int cbb = ((kk * 64) + ((lane >> 4) * 16)) ^ ((rowb & 7) << 4);
        bfv[i] = *(const s16x8*)(BsB + rowb * 128 + cbb);
      }
#pragma unroll
      for (int i = 0; i < 4; ++i)
#pragma unroll
        for (int j = 0; j < 4; ++j)
          acc[i][j] = MFMA32(af[i], bfv[j], acc[i][j]);
    }
    __syncthreads();
  }

  const int lr = (lane >> 4) * 4;
  const int lc = lane & 15;
  if constexpr (EPI == 2) {
    bf16* C = (bf16*)Cp;
#pragma unroll
    for (int i = 0; i < 4; ++i)
#pragma unroll
      for (int j = 0; j < 4; ++j) {
        int n = bn0 + wn * 64 + j * 16 + lc;
        int kvh = n >> 7, d = n & 127;
        int m = bm0 + wm * 64 + i * 16 + lr;
        int b = m >> 12, s0i = m & (CS - 1);
        bf16x4 pk;
        pk[0] = (bf16)acc[i][j][0]; pk[1] = (bf16)acc[i][j][1];
        pk[2] = (bf16)acc[i][j][2]; pk[3] = (bf16)acc[i][j][3];
        *(bf16x4*)(C + (((size_t)b * CHKV + kvh) * CHD + d) * CS + s0i) = pk;
      }
  } else if constexpr (EPI == 3) {
    bf16* C = (bf16*)Cp;
#pragma unroll
    for (int i = 0; i < 4; ++i)
#pragma unroll
      for (int j = 0; j < 4; ++j) {
        int n = bn0 + wn * 64 + j * 16 + lc;
        int kvh = n >> 7, d = n & 127;
        int m = bm0 + wm * 64 + i * 16 + lr;
        int b = m >> 12, s0i = m & (CS - 1);
#pragma unroll
        for (int r = 0; r < 4; ++r)
          C[(((size_t)b * CHKV + kvh) * CS + (s0i + r)) * CHD + d] = (bf16)acc[i][j][r];
      }
  } else {
#pragma unroll
    for (int i = 0; i < 4; ++i)
#pragma unroll
      for (int j = 0; j < 4; ++j) {
        int n = bn0 + wn * 64 + j * 16 + lc;
        int m = bm0 + wm * 64 + i * 16 + lr;
#pragma unroll
        for (int r = 0; r < 4; ++r) {
          if constexpr (EPI == 0)
            ((float*)Cp)[(size_t)(m + r) * N + n] = acc[i][j][r];
          else
            ((bf16*)Cp)[(size_t)(m + r) * N + n] = (bf16)acc[i][j][r];
        }
      }
  }
}

// -------------------------------------------------------------- attention ----
// Block = (b, kv, 32-q tile); 4 waves = 4 GQA heads. K chunk [32][256B] and
// V^T chunk [128][64B] staged in LDS (double-buffered, 1 barrier/chunk),
// XOR-swizzled on both sides. Swapped QK^T (mfma(K,Q)); PV uses 16x16x16 so
// the score frag feeds PV directly (zero cross-lane shuffles).
__global__ __launch_bounds__(256) void k_attn(const bf16* __restrict__ Q,
                                              const bf16* __restrict__ Kb,
                                              const bf16* __restrict__ Vt,
                                              bf16* __restrict__ O) {
  __shared__ alignas(16) char lds[2][16384];   // [buf][K 8KB | V 8KB]
  int blk = (int)blockIdx.x;
  blk = (blk & 7) * 128 + (blk >> 3);          // XCD-chunked swizzle (nwg=1024)
  const int qt = blk & 127;
  const int kv = (blk >> 7) & 3;
  const int b  = blk >> 9;
  const int tid = threadIdx.x;
  const int lane = tid & 63, wv = tid >> 6;
  const int g = lane >> 4, qi = lane & 15;
  const int h = kv * 4 + wv;
  const int q0 = qt * 32;
  const float SCL2 = 0.1275174308f;            // (1/sqrt(128)) * log2(e)

  // Q fragments (B-operand of swapped QK): col=q=qi, k = g*8+j (+32t)
  s16x8 qf[2][4];
#pragma unroll
  for (int sub = 0; sub < 2; ++sub) {
    const bf16* qb_ = Q + (((size_t)b * CS + q0 + sub * 16 + qi) * CHQ + h) * CHD + g * 8;
#pragma unroll
    for (int t = 0; t < 4; ++t) qf[sub][t] = *(const s16x8*)(qb_ + t * 32);
  }

  f32x4 ot[2][8];
#pragma unroll
  for (int sub = 0; sub < 2; ++sub)
#pragma unroll
    for (int t = 0; t < 8; ++t) ot[sub][t] = (f32x4){0.f, 0.f, 0.f, 0.f};
  float m_run[2] = {-__builtin_inff(), -__builtin_inff()};
  float l_run[2] = {0.f, 0.f};

  const int kstart = (q0 >= CW) ? (q0 - CW) : 0;
  const int nc = (q0 + 32 - kstart) >> 5;

  const char* Kbase = (const char*)Kb + (size_t)(b * CHKV + kv) * CS * 256;
  const char* Vbase = (const char*)Vt + (size_t)(b * CHKV + kv) * CHD * (CS * 2);

  // staging source offsets (per-lane); LDS dest is wave-uniform + lane*16.
  const int krow = tid >> 4;                   // 0..15
  const int kcol = (tid & 15) * 16;
  const int ksw0 = krow * 256 + (kcol ^ ((krow & 7) << 4));
  const int ksw1 = (krow + 16) * 256 + (kcol ^ ((krow & 7) << 4)); // (r+16)&7==r&7
  const int vrow = tid >> 2;                   // 0..63
  const int vcol = (tid & 3) * 16;
  const size_t vsw0 = (size_t)vrow * (CS * 2) + (vcol ^ ((vrow & 3) << 4));
  const size_t vsw1 = (size_t)(vrow + 64) * (CS * 2) + (vcol ^ ((vrow & 3) << 4));

#define STAGE(kc_, buf_) do {                                                   \
    const char* kS_ = Kbase + (size_t)(kc_) * 256;                              \
    const char* vS_ = Vbase + (size_t)(kc_) * 2;                                \
    char* d_ = (char*)lds[buf_];                                                \
    __builtin_amdgcn_global_load_lds(                                           \
        (const __attribute__((address_space(1))) void*)(kS_ + ksw0),            \
        (__attribute__((address_space(3))) void*)(d_ + wv * 1024), 16, 0, 0);   \
    __builtin_amdgcn_global_load_lds(                                           \
        (const __attribute__((address_space(1))) void*)(kS_ + ksw1),            \
        (__attribute__((address_space(3))) void*)(d_ + 4096 + wv * 1024), 16, 0, 0); \
    __builtin_amdgcn_global_load_lds(                                           \
        (const __attribute__((address_space(1))) void*)(vS_ + vsw0),            \
        (__attribute__((address_space(3))) void*)(d_ + 8192 + wv * 1024), 16, 0, 0); \
    __builtin_amdgcn_global_load_lds(                                           \
        (const __attribute__((address_space(1))) void*)(vS_ + vsw1),            \
        (__attribute__((address_space(3))) void*)(d_ + 12288 + wv * 1024), 16, 0, 0); \
  } while (0)

  STAGE(kstart, 0);
  __syncthreads();
  int cur = 0;

  for (int c = 0; c < nc; ++c) {
    const int kc = kstart + c * 32;
    if (c + 1 < nc) STAGE(kc + 32, cur ^ 1);

    const char* KL = (const char*)lds[cur];
    const char* VL = (const char*)lds[cur] + 8192;

    // QK^T (swapped): sc[sub][half], D row=key (g*4+r), col=q (qi)
    f32x4 sc[2][2];
    sc[0][0] = (f32x4){0.f,0.f,0.f,0.f}; sc[0][1] = (f32x4){0.f,0.f,0.f,0.f};
    sc[1][0] = (f32x4){0.f,0.f,0.f,0.f}; sc[1][1] = (f32x4){0.f,0.f,0.f,0.f};
    __builtin_amdgcn_s_setprio(1);
#pragma unroll
    for (int t = 0; t < 4; ++t) {
      const int co = (t * 64 + g * 16) ^ ((qi & 7) << 4);
      s16x8 k0 = *(const s16x8*)(KL + qi * 256 + co);
      s16x8 k1 = *(const s16x8*)(KL + 4096 + qi * 256 + co);
      sc[0][0] = MFMA32(k0, qf[0][t], sc[0][0]);
      sc[0][1] = MFMA32(k1, qf[0][t], sc[0][1]);
      sc[1][0] = MFMA32(k0, qf[1][t], sc[1][0]);
      sc[1][1] = MFMA32(k1, qf[1][t], sc[1][1]);
    }
    __builtin_amdgcn_s_setprio(0);

    // online softmax (base-2 domain), defer-rescale THR=11.5 bits (~8 nats)
    s16x4 pb[2][2];
#pragma unroll
    for (int sub = 0; sub < 2; ++sub) {
      const int qg = q0 + sub * 16 + qi;
      float p[8];
#pragma unroll
      for (int hf = 0; hf < 2; ++hf)
#pragma unroll
        for (int r = 0; r < 4; ++r) {
          int key = kc + hf * 16 + g * 4 + r;
          float v = sc[sub][hf][r] * SCL2;
          p[hf * 4 + r] = (key <= qg && key + CW >= qg) ? v : -__builtin_inff();
        }
      float pm = fmaxf(fmaxf(fmaxf(p[0], p[1]), fmaxf(p[2], p[3])),
                       fmaxf(fmaxf(p[4], p[5]), fmaxf(p[6], p[7])));
      pm = fmaxf(pm, __shfl_xor(pm, 16));
      pm = fmaxf(pm, __shfl_xor(pm, 32));
      if (__any(pm - m_run[sub] > 11.5f)) {
        float mn = fmaxf(m_run[sub], pm);
        float fs = exp2f(m_run[sub] - mn);   // first chunk: exp2(-inf)=0
        l_run[sub] *= fs;
#pragma unroll
        for (int t = 0; t < 8; ++t) {
          ot[sub][t][0] *= fs; ot[sub][t][1] *= fs;
          ot[sub][t][2] *= fs; ot[sub][t][3] *= fs;
        }
        m_run[sub] = mn;
      }
      float rs = 0.f;
#pragma unroll
      for (int i2 = 0; i2 < 8; ++i2) { p[i2] = exp2f(p[i2] - m_run[sub]); rs += p[i2]; }
      rs += __shfl_xor(rs, 16);
      rs += __shfl_xor(rs, 32);
      l_run[sub] += rs;
#pragma unroll
      for (int j = 0; j < 4; ++j) {
        pb[sub][0][j] = __builtin_bit_cast(short, (bf16)p[j]);
        pb[sub][1][j] = __builtin_bit_cast(short, (bf16)p[4 + j]);
      }
    }

    // PV: O^T[d][q] += V^T[d][k] P^T[k][q]; score frag IS the B-frag (k=g*4+j)
    __builtin_amdgcn_s_setprio(1);
#pragma unroll
    for (int t = 0; t < 8; ++t) {
      const int rowd = t * 16 + qi;
      const int sw = (rowd & 3) << 4;
      s16x4 v0 = *(const s16x4*)(VL + rowd * 64 + ((g * 8) ^ sw));
      s16x4 v1 = *(const s16x4*)(VL + rowd * 64 + ((32 + g * 8) ^ sw));
      ot[0][t] = MFMA16(v0, pb[0][0], ot[0][t]);
      ot[0][t] = MFMA16(v1, pb[0][1], ot[0][t]);
      ot[1][t] = MFMA16(v0, pb[1][0], ot[1][t]);
      ot[1][t] = MFMA16(v1, pb[1][1], ot[1][t]);
    }
    __builtin_amdgcn_s_setprio(0);

    __syncthreads();   // stage(c+1) complete + all waves done with lds[cur]
    cur ^= 1;
  }
#undef STAGE

#pragma unroll
  for (int sub = 0; sub < 2; ++sub) {
    float invl = 1.0f / l_run[sub];
    bf16* ob = O + (((size_t)b * CS + q0 + sub * 16 + qi) * CHQ + h) * CHD;
#pragma unroll
    for (int t = 0; t < 8; ++t) {
      bf16x4 pk;
      pk[0] = (bf16)(ot[sub][t][0] * invl);
      pk[1] = (bf16)(ot[sub][t][1] * invl);
      pk[2] = (bf16)(ot[sub][t][2] * invl);
      pk[3] = (bf16)(ot[sub][t][3] * invl);
      *(bf16x4*)(ob + t * 16 + g * 4) = pk;
    }
  }
}

// ------------------------------------------------------------------ launch ---
extern "C" void kernel_launch(void* const* d_in, const int* in_sizes, int n_in,
                              void* d_out, int out_size, void* d_ws, size_t ws_size,
                              hipStream_t stream) {
  const float* x = (const float*)d_in[0];
  const float* g = (const float*)d_in[1];
  const float* wq = (const float*)d_in[2];
  const float* wk = (const float*)d_in[3];
  const float* wv = (const float*)d_in[4];
  const float* wo = (const float*)d_in[5];
  float* out = (float*)d_out;

  char* p = (char*)d_ws;
  bf16* xn = (bf16*)p;  p += (size_t)CM * CD * 2;            // 32 MiB
  bf16* wqT = (bf16*)p; p += (size_t)CD * CD * 2;            //  8 MiB
  bf16* wkT = (bf16*)p; p += (size_t)(CHKV * CHD) * CD * 2;  //  2 MiB
  bf16* wvT = (bf16*)p; p += (size_t)(CHKV * CHD) * CD * 2;  //  2 MiB
  bf16* woT = (bf16*)p; p += (size_t)CD * CD * 2;            //  8 MiB
  double* invT = (double*)p; p += 64 * 8;
  float* cosT = (float*)p; p += (size_t)CS * 64 * 4;         //  1 MiB
  float* sinT = (float*)p; p += (size_t)CS * 64 * 4;         //  1 MiB
  bf16* qb = (bf16*)p;  p += (size_t)CM * CD * 2;            // 32 MiB
  bf16* kb = (bf16*)p;  p += (size_t)CM * (CHKV * CHD) * 2;  //  8 MiB [b][kv][s][d]
  bf16* vT = (bf16*)p;  p += (size_t)CM * (CHKV * CHD) * 2;  //  8 MiB [b][kv][d][s]
  bf16* ao = xn;  // alias: xn dead after the V projection GEMM

  k_rope_inv<<<1, 64, 0, stream>>>(invT);
  k_rope_tables<<<(CS * 64) / 256, 256, 0, stream>>>(invT, cosT, sinT);
  k_rmsnorm<<<CM, 256, 0, stream>>>(x, g, xn);
  k_transpose<<<dim3(CD / 32, CD / 32), 256, 0, stream>>>(wq, wqT, CD, CD);
  k_transpose<<<dim3((CHKV * CHD) / 32, CD / 32), 256, 0, stream>>>(wk, wkT, CD, CHKV * CHD);
  k_transpose<<<dim3((CHKV * CHD) / 32, CD / 32), 256, 0, stream>>>(wv, wvT, CD, CHKV * CHD);
  k_transpose<<<dim3(CD / 32, CD / 32), 256, 0, stream>>>(wo, woT, CD, CD);

  k_gemm<1><<<dim3(CD / BN, CM / BM), 256, 0, stream>>>(xn, wqT, qb, CM, CD, CD);
  k_gemm<3><<<dim3((CHKV * CHD) / BN, CM / BM), 256, 0, stream>>>(xn, wkT, kb, CM, CHKV * CHD, CD);
  k_gemm<2><<<dim3((CHKV * CHD) / BN, CM / BM), 256, 0, stream>>>(xn, wvT, vT, CM, CHKV * CHD, CD);

  k_rope<<<(CM * CHQ * 64) / 256, 256, 0, stream>>>(qb, cosT, sinT, 4);   // Q: [b][s][16][d]
  k_rope<<<(CM * CHKV * 64) / 256, 256, 0, stream>>>(kb, cosT, sinT, 0);  // K: [b][kv][s][d]

  k_attn<<<CB * CHKV * (CS / 32), 256, 0, stream>>>(qb, kb, vT, ao);

  k_gemm<0><<<dim3(CD / BN, CM / BM), 256, 0, stream>>>(ao, woT, out, CM, CD, CD);
}

// Round 7
// 460.832 us; speedup vs baseline: 1.5540x; 1.1678x over previous
//
#include <hip/hip_runtime.h>
#include <math.h>

typedef __bf16 bf16;
typedef short  s16x8  __attribute__((ext_vector_type(8)));  // MFMA A/B frag (8 bf16)
typedef short  s16x4  __attribute__((ext_vector_type(4)));  // MFMA A/B frag (4 bf16)
typedef __bf16 bf16x4 __attribute__((ext_vector_type(4)));
typedef __bf16 bf16x2 __attribute__((ext_vector_type(2)));
typedef float  f32x4  __attribute__((ext_vector_type(4)));

constexpr int CB = 2, CS = 4096, CD = 2048, CHQ = 16, CHKV = 4, CHD = 128, CW = 512;
constexpr int CM = CB * CS;   // 8192 rows

#define MFMA32(a, b, c) __builtin_amdgcn_mfma_f32_16x16x32_bf16((a), (b), (c), 0, 0, 0)

#if defined(__has_builtin)
#if __has_builtin(__builtin_amdgcn_mfma_f32_16x16x16bf16_1k)
#define HAVE_MFMA16_1K 1
#endif
#endif

static __device__ __forceinline__ f32x4 MFMA16(s16x4 a, s16x4 b, f32x4 c) {
#ifdef HAVE_MFMA16_1K
  return __builtin_amdgcn_mfma_f32_16x16x16bf16_1k(a, b, c, 0, 0, 0);
#else
  asm volatile("v_mfma_f32_16x16x16_bf16 %0, %1, %2, %0" : "+v"(c) : "v"(a), "v"(b));
  return c;
#endif
}

// ---------------------------------------------------------------- RMSNorm ---
__global__ __launch_bounds__(256) void k_rmsnorm(const float* __restrict__ x,
                                                 const float* __restrict__ g,
                                                 bf16* __restrict__ xn) {
  const int row = blockIdx.x;
  const int tid = threadIdx.x;
  const float* xr = x + (size_t)row * CD;
  float4 v0 = *(const float4*)(xr + tid * 4);
  float4 v1 = *(const float4*)(xr + tid * 4 + 1024);
  float ss = v0.x * v0.x + v0.y * v0.y + v0.z * v0.z + v0.w * v0.w
           + v1.x * v1.x + v1.y * v1.y + v1.z * v1.z + v1.w * v1.w;
#pragma unroll
  for (int o = 1; o < 64; o <<= 1) ss += __shfl_xor(ss, o);
  __shared__ float red[4];
  if ((tid & 63) == 0) red[tid >> 6] = ss;
  __syncthreads();
  float tot = red[0] + red[1] + red[2] + red[3];
  float inv = rsqrtf(tot * (1.0f / CD) + 1e-6f);
  float4 g0 = *(const float4*)(g + tid * 4);
  float4 g1 = *(const float4*)(g + tid * 4 + 1024);
  bf16x4 o0, o1;
  o0[0] = (bf16)(v0.x * inv * g0.x); o0[1] = (bf16)(v0.y * inv * g0.y);
  o0[2] = (bf16)(v0.z * inv * g0.z); o0[3] = (bf16)(v0.w * inv * g0.w);
  o1[0] = (bf16)(v1.x * inv * g1.x); o1[1] = (bf16)(v1.y * inv * g1.y);
  o1[2] = (bf16)(v1.z * inv * g1.z); o1[3] = (bf16)(v1.w * inv * g1.w);
  *(bf16x4*)(xn + (size_t)row * CD + tid * 4) = o0;
  *(bf16x4*)(xn + (size_t)row * CD + tid * 4 + 1024) = o1;
}

// --------------------------- all-weights transpose fp32 -> bf16 (1 dispatch) --
// wq -> wqkvT rows 0..2047; wk -> rows 2048..2559; wv -> rows 2560..3071;
// wo -> woT. All dst row strides = 2048 (the K dim).
__global__ __launch_bounds__(256) void k_transpose_all(
    const float* __restrict__ wq, const float* __restrict__ wk,
    const float* __restrict__ wv, const float* __restrict__ wo,
    bf16* __restrict__ wqkvT, bf16* __restrict__ woT) {
  __shared__ float tile[32][33];
  int bid = blockIdx.x;
  const float* src; bf16* dst; int N_;
  if (bid < 4096)      { src = wq; dst = wqkvT;                          N_ = 2048; }
  else if (bid < 5120) { src = wk; dst = wqkvT + (size_t)2048 * 2048;    N_ = 512;  bid -= 4096; }
  else if (bid < 6144) { src = wv; dst = wqkvT + (size_t)2560 * 2048;    N_ = 512;  bid -= 5120; }
  else                 { src = wo; dst = woT;                            N_ = 2048; bid -= 6144; }
  const int ntx = N_ >> 5;
  const int bx = bid & (ntx - 1), by = bid / ntx;
  const int tx = threadIdx.x & 31, ty = threadIdx.x >> 5;
  const int c0 = bx * 32, r0 = by * 32;
#pragma unroll
  for (int i = 0; i < 32; i += 8)
    tile[ty + i][tx] = src[(size_t)(r0 + ty + i) * N_ + c0 + tx];
  __syncthreads();
#pragma unroll
  for (int i = 0; i < 32; i += 8)
    dst[(size_t)(c0 + ty + i) * 2048 + r0 + tx] = (bf16)tile[tx][ty + i];
}

// ------------------------------------------------------------- RoPE tables ---
__global__ void k_rope_inv(double* __restrict__ inv) {
  int i = threadIdx.x;
  if (i < 64) inv[i] = pow(10000.0, -(double)i / 64.0);
}

__global__ __launch_bounds__(256) void k_rope_tables(const double* __restrict__ inv,
                                                     float* __restrict__ cosT,
                                                     float* __restrict__ sinT) {
  int idx = blockIdx.x * 256 + threadIdx.x;  // S*64
  int s = idx >> 6, i = idx & 63;
  double f = (double)s * inv[i];
  double n = floor(f * 0.15915494309189535 + 0.5);
  float r = (float)(f - n * 6.283185307179586);
  cosT[idx] = cosf(r);
  sinT[idx] = sinf(r);
}

// ----------------------------------------- RoPE apply, Q and K in one grid ---
// Q: [b][s][16][64 pairs]  (s at pair-bit 10);  K: [b][kv][s][64 pairs] (bit 6)
constexpr size_t NQP = (size_t)CM * CHQ * 64;                 // Q pair count
__global__ __launch_bounds__(256) void k_rope2(bf16* __restrict__ qb,
                                               bf16* __restrict__ kb,
                                               const float* __restrict__ cosT,
                                               const float* __restrict__ sinT) {
  size_t idx = (size_t)blockIdx.x * 256 + threadIdx.x;
  bf16* ptr; int s, i;
  if (idx < NQP) {
    i = (int)(idx & 63); s = (int)((idx >> 10) & (CS - 1)); ptr = qb + 2 * idx;
  } else {
    size_t j = idx - NQP;
    i = (int)(j & 63); s = (int)((j >> 6) & (CS - 1)); ptr = kb + 2 * j;
  }
  bf16x2 p = *(bf16x2*)ptr;
  float xe = (float)p[0], xo = (float)p[1];
  float c = cosT[s * 64 + i], sn = sinT[s * 64 + i];
  bf16x2 o;
  o[0] = (bf16)(xe * c - xo * sn);
  o[1] = (bf16)(xe * sn + xo * c);
  *(bf16x2*)ptr = o;
}

// ------------------------------------------------------------------- GEMM ----
// C = A[M][K] * Bt[N][K]^T. 128x128 tile, BK=64, 4 waves, 16x16x32 MFMA.
// EPI 0: fp32 natural (row stride N).
// EPI 4: merged QKV epilogue — n<2048 -> qb natural bf16 [b][s][16][d];
//        2048..2559 -> kb [b][kv][s][d]; >=2560 -> vT [b][kv][d][s].
constexpr int BM = 128, BN = 128, BK = 64;

template <int EPI>
__global__ __launch_bounds__(256)
void k_gemm(const bf16* __restrict__ A, const bf16* __restrict__ Bt,
            void* __restrict__ Cp, bf16* __restrict__ Ck, bf16* __restrict__ Cv,
            int M, int N, int K) {
  __shared__ alignas(16) bf16 As[BM * BK];
  __shared__ alignas(16) bf16 Bs[BN * BK];
  const int tid = threadIdx.x;
  const int wave = tid >> 6;
  const int lane = tid & 63;
  const int bn0 = blockIdx.x * BN;
  const int bm0 = blockIdx.y * BM;
  const int wm = wave >> 1, wn = wave & 1;

  int segBase[4], srcOff[4];
#pragma unroll
  for (int i = 0; i < 4; ++i) {
    int o = ((i * 4 + wave) << 10) + lane * 16;
    int r = o >> 7;
    int cb = (o & 127) ^ ((r & 7) << 4);
    segBase[i] = (i * 4 + wave) << 10;
    srcOff[i] = r * (K * 2) + cb;
  }
  const char* Abase = (const char*)A + (size_t)bm0 * (K * 2);
  const char* Bbase = (const char*)Bt + (size_t)bn0 * (K * 2);
  char* AsB = (char*)As;
  char* BsB = (char*)Bs;

  f32x4 acc[4][4];
#pragma unroll
  for (int i = 0; i < 4; ++i)
#pragma unroll
    for (int j = 0; j < 4; ++j) acc[i][j] = (f32x4){0.f, 0.f, 0.f, 0.f};

  const int nkt = K >> 6;
  for (int kt = 0; kt < nkt; ++kt) {
#pragma unroll
    for (int i = 0; i < 4; ++i)
      __builtin_amdgcn_global_load_lds(
          (const __attribute__((address_space(1))) void*)(Abase + srcOff[i] + kt * 128),
          (__attribute__((address_space(3))) void*)(AsB + segBase[i]), 16, 0, 0);
#pragma unroll
    for (int i = 0; i < 4; ++i)
      __builtin_amdgcn_global_load_lds(
          (const __attribute__((address_space(1))) void*)(Bbase + srcOff[i] + kt * 128),
          (__attribute__((address_space(3))) void*)(BsB + segBase[i]), 16, 0, 0);
    __syncthreads();
#pragma unroll
    for (int kk = 0; kk < 2; ++kk) {
      s16x8 af[4], bfv[4];
#pragma unroll
      for (int i = 0; i < 4; ++i) {
        int row = wm * 64 + i * 16 + (lane & 15);
        int cb = ((kk * 64) + ((lane >> 4) * 16)) ^ ((row & 7) << 4);
        af[i] = *(const s16x8*)(AsB + row * 128 + cb);
        int rowb = wn * 64 + i * 16 + (lane & 15);
        int cbb = ((kk * 64) + ((lane >> 4) * 16)) ^ ((rowb & 7) << 4);
        bfv[i] = *(const s16x8*)(BsB + rowb * 128 + cbb);
      }
#pragma unroll
      for (int i = 0; i < 4; ++i)
#pragma unroll
        for (int j = 0; j < 4; ++j)
          acc[i][j] = MFMA32(af[i], bfv[j], acc[i][j]);
    }
    __syncthreads();
  }

  const int lr = (lane >> 4) * 4;
  const int lc = lane & 15;
  if constexpr (EPI == 4) {
    if (bn0 < 2048) {               // Q natural: qb[m][n], stride 2048
      bf16* C = (bf16*)Cp;
#pragma unroll
      for (int i = 0; i < 4; ++i)
#pragma unroll
        for (int j = 0; j < 4; ++j) {
          int n = bn0 + wn * 64 + j * 16 + lc;
          int m = bm0 + wm * 64 + i * 16 + lr;
#pragma unroll
          for (int r = 0; r < 4; ++r)
            C[(size_t)(m + r) * 2048 + n] = (bf16)acc[i][j][r];
        }
    } else if (bn0 < 2560) {        // K: kb[b][kv][s][d]
#pragma unroll
      for (int i = 0; i < 4; ++i)
#pragma unroll
        for (int j = 0; j < 4; ++j) {
          int n = bn0 - 2048 + wn * 64 + j * 16 + lc;
          int kvh = n >> 7, d = n & 127;
          int m = bm0 + wm * 64 + i * 16 + lr;
          int b = m >> 12, s0i = m & (CS - 1);
#pragma unroll
          for (int r = 0; r < 4; ++r)
            Ck[(((size_t)b * CHKV + kvh) * CS + (s0i + r)) * CHD + d] = (bf16)acc[i][j][r];
        }
    } else {                        // V^T: vT[b][kv][d][s]
#pragma unroll
      for (int i = 0; i < 4; ++i)
#pragma unroll
        for (int j = 0; j < 4; ++j) {
          int n = bn0 - 2560 + wn * 64 + j * 16 + lc;
          int kvh = n >> 7, d = n & 127;
          int m = bm0 + wm * 64 + i * 16 + lr;
          int b = m >> 12, s0i = m & (CS - 1);
          bf16x4 pk;
          pk[0] = (bf16)acc[i][j][0]; pk[1] = (bf16)acc[i][j][1];
          pk[2] = (bf16)acc[i][j][2]; pk[3] = (bf16)acc[i][j][3];
          *(bf16x4*)(Cv + (((size_t)b * CHKV + kvh) * CHD + d) * CS + s0i) = pk;
        }
    }
  } else {                          // fp32 natural
#pragma unroll
    for (int i = 0; i < 4; ++i)
#pragma unroll
      for (int j = 0; j < 4; ++j) {
        int n = bn0 + wn * 64 + j * 16 + lc;
        int m = bm0 + wm * 64 + i * 16 + lr;
#pragma unroll
        for (int r = 0; r < 4; ++r)
          ((float*)Cp)[(size_t)(m + r) * N + n] = acc[i][j][r];
      }
  }
}

// -------------------------------------------------------------- attention ----
// Block = (b, kv, 32-q tile); 4 waves = 4 GQA heads. K chunk [32 keys][256B]
// and V^T chunk in pair-rows [64][128B] (2 d-rows per LDS row so the (r&7)<<4
// swizzle mixes qi>>1..qi>>3 into the bank index — uniform 4 lanes/bank-pair
// = the b64 floor). Double-buffered, 1 barrier/chunk. Interior chunks (15 of
// 17) skip masking entirely.
__global__ __launch_bounds__(256) void k_attn(const bf16* __restrict__ Q,
                                              const bf16* __restrict__ Kb,
                                              const bf16* __restrict__ Vt,
                                              bf16* __restrict__ O) {
  __shared__ alignas(16) char lds[2][16384];   // [buf][K 8KB | V 8KB]
  int blk = (int)blockIdx.x;
  blk = (blk & 7) * 128 + (blk >> 3);          // XCD-chunked swizzle (nwg=1024)
  const int qt = blk & 127;
  const int kv = (blk >> 7) & 3;
  const int b  = blk >> 9;
  const int tid = threadIdx.x;
  const int lane = tid & 63, wv = tid >> 6;
  const int g = lane >> 4, qi = lane & 15;
  const int h = kv * 4 + wv;
  const int q0 = qt * 32;
  const float SCL2 = 0.1275174308f;            // (1/sqrt(128)) * log2(e)

  // Q fragments (B-operand of swapped QK): col=q=qi, k = g*8+j (+32t)
  s16x8 qf[2][4];
#pragma unroll
  for (int sub = 0; sub < 2; ++sub) {
    const bf16* qb_ = Q + (((size_t)b * CS + q0 + sub * 16 + qi) * CHQ + h) * CHD + g * 8;
#pragma unroll
    for (int t = 0; t < 4; ++t) qf[sub][t] = *(const s16x8*)(qb_ + t * 32);
  }

  f32x4 ot[2][8];
#pragma unroll
  for (int sub = 0; sub < 2; ++sub)
#pragma unroll
    for (int t = 0; t < 8; ++t) ot[sub][t] = (f32x4){0.f, 0.f, 0.f, 0.f};
  float m_run[2] = {-__builtin_inff(), -__builtin_inff()};
  float l_run[2] = {0.f, 0.f};

  const int kstart = (q0 >= CW) ? (q0 - CW) : 0;
  const int nc = (q0 + 32 - kstart) >> 5;

  const char* Kbase = (const char*)Kb + (size_t)(b * CHKV + kv) * CS * 256;
  const char* Vbase = (const char*)Vt + (size_t)(b * CHKV + kv) * CHD * (CS * 2);

  // K staging: rows 0..15 / 16..31, 16B per thread, swizzle (r&7)<<4.
  const int krow = tid >> 4;
  const int kcol = (tid & 15) * 16;
  const int ksw0 = krow * 256 + (kcol ^ ((krow & 7) << 4));
  const int ksw1 = (krow + 16) * 256 + (kcol ^ ((krow & 7) << 4));
  // V staging: LDS byte A=tid*16 (+4096); pair-row r=A>>7, L=(A&127)^((r&7)<<4),
  // d = 2r + (L>>6), keybyte = L&63. Second load is d+64 (same L: (r+32)&7==r&7).
  const int vA = tid * 16;
  const int vr0 = vA >> 7;
  const int vL = (vA & 127) ^ ((vr0 & 7) << 4);
  const size_t vsw0 = (size_t)(2 * vr0 + (vL >> 6)) * (CS * 2) + (vL & 63);
  const size_t vsw1 = vsw0 + (size_t)64 * (CS * 2);

#define STAGE(kc_, buf_) do {                                                   \
    const char* kS_ = Kbase + (size_t)(kc_) * 256;                              \
    const char* vS_ = Vbase + (size_t)(kc_) * 2;                                \
    char* d_ = (char*)lds[buf_];                                                \
    __builtin_amdgcn_global_load_lds(                                           \
        (const __attribute__((address_space(1))) void*)(kS_ + ksw0),            \
        (__attribute__((address_space(3))) void*)(d_ + wv * 1024), 16, 0, 0);   \
    __builtin_amdgcn_global_load_lds(                                           \
        (const __attribute__((address_space(1))) void*)(kS_ + ksw1),            \
        (__attribute__((address_space(3))) void*)(d_ + 4096 + wv * 1024), 16, 0, 0); \
    __builtin_amdgcn_global_load_lds(                                           \
        (const __attribute__((address_space(1))) void*)(vS_ + vsw0),            \
        (__attribute__((address_space(3))) void*)(d_ + 8192 + wv * 1024), 16, 0, 0); \
    __builtin_amdgcn_global_load_lds(                                           \
        (const __attribute__((address_space(1))) void*)(vS_ + vsw1),            \
        (__attribute__((address_space(3))) void*)(d_ + 12288 + wv * 1024), 16, 0, 0); \
  } while (0)

  STAGE(kstart, 0);
  __syncthreads();
  int cur = 0;

  for (int c = 0; c < nc; ++c) {
    const int kc = kstart + c * 32;
    if (c + 1 < nc) STAGE(kc + 32, cur ^ 1);

    const char* KL = (const char*)lds[cur];
    const char* VL = (const char*)lds[cur] + 8192;

    // QK^T (swapped): D row=key (g*4+r per half), col=q (qi)
    f32x4 sc[2][2];
    sc[0][0] = (f32x4){0.f,0.f,0.f,0.f}; sc[0][1] = (f32x4){0.f,0.f,0.f,0.f};
    sc[1][0] = (f32x4){0.f,0.f,0.f,0.f}; sc[1][1] = (f32x4){0.f,0.f,0.f,0.f};
    __builtin_amdgcn_s_setprio(1);
#pragma unroll
    for (int t = 0; t < 4; ++t) {
      const int co = (t * 64 + g * 16) ^ ((qi & 7) << 4);
      s16x8 k0 = *(const s16x8*)(KL + qi * 256 + co);
      s16x8 k1 = *(const s16x8*)(KL + 4096 + qi * 256 + co);
      sc[0][0] = MFMA32(k0, qf[0][t], sc[0][0]);
      sc[0][1] = MFMA32(k1, qf[0][t], sc[0][1]);
      sc[1][0] = MFMA32(k0, qf[1][t], sc[1][0]);
      sc[1][1] = MFMA32(k1, qf[1][t], sc[1][1]);
    }
    __builtin_amdgcn_s_setprio(0);

    // interior chunks need no mask: all keys in [q-512, q] for every q in tile
    const bool edge = (kc + 31 > q0) || (kc + 481 < q0);

    s16x4 pb[2][2];
#pragma unroll
    for (int sub = 0; sub < 2; ++sub) {
      const int qg = q0 + sub * 16 + qi;
      float p[8];
      if (edge) {
#pragma unroll
        for (int hf = 0; hf < 2; ++hf)
#pragma unroll
          for (int r = 0; r < 4; ++r) {
            int key = kc + hf * 16 + g * 4 + r;
            float v = sc[sub][hf][r] * SCL2;
            p[hf * 4 + r] = (key <= qg && key + CW >= qg) ? v : -__builtin_inff();
          }
      } else {
#pragma unroll
        for (int hf = 0; hf < 2; ++hf)
#pragma unroll
          for (int r = 0; r < 4; ++r)
            p[hf * 4 + r] = sc[sub][hf][r] * SCL2;
      }
      float pm = fmaxf(fmaxf(fmaxf(p[0], p[1]), fmaxf(p[2], p[3])),
                       fmaxf(fmaxf(p[4], p[5]), fmaxf(p[6], p[7])));
      pm = fmaxf(pm, __shfl_xor(pm, 16));
      pm = fmaxf(pm, __shfl_xor(pm, 32));
      if (__any(pm - m_run[sub] > 11.5f)) {     // defer-rescale (T13), base-2
        float mn = fmaxf(m_run[sub], pm);
        float fs = exp2f(m_run[sub] - mn);      // first chunk: exp2(-inf)=0
        l_run[sub] *= fs;
#pragma unroll
        for (int t = 0; t < 8; ++t) {
          ot[sub][t][0] *= fs; ot[sub][t][1] *= fs;
          ot[sub][t][2] *= fs; ot[sub][t][3] *= fs;
        }
        m_run[sub] = mn;
      }
      float rs = 0.f;
#pragma unroll
      for (int i2 = 0; i2 < 8; ++i2) { p[i2] = exp2f(p[i2] - m_run[sub]); rs += p[i2]; }
      rs += __shfl_xor(rs, 16);
      rs += __shfl_xor(rs, 32);
      l_run[sub] += rs;
#pragma unroll
      for (int j = 0; j < 4; ++j) {
        pb[sub][0][j] = __builtin_bit_cast(short, (bf16)p[j]);
        pb[sub][1][j] = __builtin_bit_cast(short, (bf16)p[4 + j]);
      }
    }

    // PV: O^T[d][q] += V^T[d][k] P^T[k][q]; score frag IS the B-frag (k=g*4+j)
    __builtin_amdgcn_s_setprio(1);
#pragma unroll
    for (int t = 0; t < 8; ++t) {
      const int rowd = t * 16 + qi;
      const int vr_ = rowd >> 1;               // pair-row
      const int base = vr_ * 128;
      const int dsel = (rowd & 1) << 6;
      const int sw = (vr_ & 7) << 4;
      s16x4 v0 = *(const s16x4*)(VL + base + ((dsel + g * 8) ^ sw));
      s16x4 v1 = *(const s16x4*)(VL + base + ((dsel + 32 + g * 8) ^ sw));
      ot[0][t] = MFMA16(v0, pb[0][0], ot[0][t]);
      ot[0][t] = MFMA16(v1, pb[0][1], ot[0][t]);
      ot[1][t] = MFMA16(v0, pb[1][0], ot[1][t]);
      ot[1][t] = MFMA16(v1, pb[1][1], ot[1][t]);
    }
    __builtin_amdgcn_s_setprio(0);

    __syncthreads();   // stage(c+1) complete + all waves done with lds[cur]
    cur ^= 1;
  }
#undef STAGE

#pragma unroll
  for (int sub = 0; sub < 2; ++sub) {
    float invl = 1.0f / l_run[sub];
    bf16* ob = O + (((size_t)b * CS + q0 + sub * 16 + qi) * CHQ + h) * CHD;
#pragma unroll
    for (int t = 0; t < 8; ++t) {
      bf16x4 pk;
      pk[0] = (bf16)(ot[sub][t][0] * invl);
      pk[1] = (bf16)(ot[sub][t][1] * invl);
      pk[2] = (bf16)(ot[sub][t][2] * invl);
      pk[3] = (bf16)(ot[sub][t][3] * invl);
      *(bf16x4*)(ob + t * 16 + g * 4) = pk;
    }
  }
}

// ------------------------------------------------------------------ launch ---
extern "C" void kernel_launch(void* const* d_in, const int* in_sizes, int n_in,
                              void* d_out, int out_size, void* d_ws, size_t ws_size,
                              hipStream_t stream) {
  const float* x = (const float*)d_in[0];
  const float* g = (const float*)d_in[1];
  const float* wq = (const float*)d_in[2];
  const float* wk = (const float*)d_in[3];
  const float* wv = (const float*)d_in[4];
  const float* wo = (const float*)d_in[5];
  float* out = (float*)d_out;

  char* p = (char*)d_ws;
  bf16* xn = (bf16*)p;    p += (size_t)CM * CD * 2;           // 32 MiB
  bf16* wqkvT = (bf16*)p; p += (size_t)3072 * CD * 2;         // 12 MiB
  bf16* woT = (bf16*)p;   p += (size_t)CD * CD * 2;           //  8 MiB
  double* invT = (double*)p; p += 4096;
  float* cosT = (float*)p; p += (size_t)CS * 64 * 4;          //  1 MiB
  float* sinT = (float*)p; p += (size_t)CS * 64 * 4;          //  1 MiB
  bf16* qb = (bf16*)p;  p += (size_t)CM * CD * 2;             // 32 MiB
  bf16* kb = (bf16*)p;  p += (size_t)CM * (CHKV * CHD) * 2;   //  8 MiB [b][kv][s][d]
  bf16* vT = (bf16*)p;  p += (size_t)CM * (CHKV * CHD) * 2;   //  8 MiB [b][kv][d][s]
  bf16* ao = xn;  // alias: xn dead after the QKV GEMM

  k_rope_inv<<<1, 64, 0, stream>>>(invT);
  k_rope_tables<<<(CS * 64) / 256, 256, 0, stream>>>(invT, cosT, sinT);
  k_rmsnorm<<<CM, 256, 0, stream>>>(x, g, xn);
  k_transpose_all<<<10240, 256, 0, stream>>>(wq, wk, wv, wo, wqkvT, woT);

  k_gemm<4><<<dim3(3072 / BN, CM / BM), 256, 0, stream>>>(xn, wqkvT, qb, kb, vT,
                                                          CM, 3072, CD);

  k_rope2<<<(int)((NQP + (size_t)CM * CHKV * 64) / 256), 256, 0, stream>>>(qb, kb, cosT, sinT);

  k_attn<<<CB * CHKV * (CS / 32), 256, 0, stream>>>(qb, kb, vT, ao);

  k_gemm<0><<<dim3(CD / BN, CM / BM), 256, 0, stream>>>(ao, woT, out, nullptr, nullptr,
                                                        CM, CD, CD);
}

// Round 8
// 444.976 us; speedup vs baseline: 1.6093x; 1.0356x over previous
//
#include <hip/hip_runtime.h>
#include <math.h>

typedef __bf16 bf16;
typedef short  s16x8  __attribute__((ext_vector_type(8)));  // MFMA A/B frag (8 bf16)
typedef short  s16x4  __attribute__((ext_vector_type(4)));  // MFMA A/B frag (4 bf16)
typedef __bf16 bf16x4 __attribute__((ext_vector_type(4)));
typedef __bf16 bf16x2 __attribute__((ext_vector_type(2)));
typedef float  f32x4  __attribute__((ext_vector_type(4)));

constexpr int CB = 2, CS = 4096, CD = 2048, CHQ = 16, CHKV = 4, CHD = 128, CW = 512;
constexpr int CM = CB * CS;   // 8192 rows

#define MFMA32(a, b, c) __builtin_amdgcn_mfma_f32_16x16x32_bf16((a), (b), (c), 0, 0, 0)
#define AS1 __attribute__((address_space(1)))
#define AS3 __attribute__((address_space(3)))

#if defined(__has_builtin)
#if __has_builtin(__builtin_amdgcn_mfma_f32_16x16x16bf16_1k)
#define HAVE_MFMA16_1K 1
#endif
#endif

static __device__ __forceinline__ f32x4 MFMA16(s16x4 a, s16x4 b, f32x4 c) {
#ifdef HAVE_MFMA16_1K
  return __builtin_amdgcn_mfma_f32_16x16x16bf16_1k(a, b, c, 0, 0, 0);
#else
  asm volatile("v_mfma_f32_16x16x16_bf16 %0, %1, %2, %0" : "+v"(c) : "v"(a), "v"(b));
  return c;
#endif
}

// ---------------------------------------------------------------- RMSNorm ---
__global__ __launch_bounds__(256) void k_rmsnorm(const float* __restrict__ x,
                                                 const float* __restrict__ g,
                                                 bf16* __restrict__ xn) {
  const int row = blockIdx.x;
  const int tid = threadIdx.x;
  const float* xr = x + (size_t)row * CD;
  float4 v0 = *(const float4*)(xr + tid * 4);
  float4 v1 = *(const float4*)(xr + tid * 4 + 1024);
  float ss = v0.x * v0.x + v0.y * v0.y + v0.z * v0.z + v0.w * v0.w
           + v1.x * v1.x + v1.y * v1.y + v1.z * v1.z + v1.w * v1.w;
#pragma unroll
  for (int o = 1; o < 64; o <<= 1) ss += __shfl_xor(ss, o);
  __shared__ float red[4];
  if ((tid & 63) == 0) red[tid >> 6] = ss;
  __syncthreads();
  float tot = red[0] + red[1] + red[2] + red[3];
  float inv = rsqrtf(tot * (1.0f / CD) + 1e-6f);
  float4 g0 = *(const float4*)(g + tid * 4);
  float4 g1 = *(const float4*)(g + tid * 4 + 1024);
  bf16x4 o0, o1;
  o0[0] = (bf16)(v0.x * inv * g0.x); o0[1] = (bf16)(v0.y * inv * g0.y);
  o0[2] = (bf16)(v0.z * inv * g0.z); o0[3] = (bf16)(v0.w * inv * g0.w);
  o1[0] = (bf16)(v1.x * inv * g1.x); o1[1] = (bf16)(v1.y * inv * g1.y);
  o1[2] = (bf16)(v1.z * inv * g1.z); o1[3] = (bf16)(v1.w * inv * g1.w);
  *(bf16x4*)(xn + (size_t)row * CD + tid * 4) = o0;
  *(bf16x4*)(xn + (size_t)row * CD + tid * 4 + 1024) = o1;
}

// --------------------------- all-weights transpose fp32 -> bf16 (1 dispatch) --
__global__ __launch_bounds__(256) void k_transpose_all(
    const float* __restrict__ wq, const float* __restrict__ wk,
    const float* __restrict__ wv, const float* __restrict__ wo,
    bf16* __restrict__ wqkvT, bf16* __restrict__ woT) {
  __shared__ float tile[32][33];
  int bid = blockIdx.x;
  const float* src; bf16* dst; int N_;
  if (bid < 4096)      { src = wq; dst = wqkvT;                          N_ = 2048; }
  else if (bid < 5120) { src = wk; dst = wqkvT + (size_t)2048 * 2048;    N_ = 512;  bid -= 4096; }
  else if (bid < 6144) { src = wv; dst = wqkvT + (size_t)2560 * 2048;    N_ = 512;  bid -= 5120; }
  else                 { src = wo; dst = woT;                            N_ = 2048; bid -= 6144; }
  const int ntx = N_ >> 5;
  const int bx = bid & (ntx - 1), by = bid / ntx;
  const int tx = threadIdx.x & 31, ty = threadIdx.x >> 5;
  const int c0 = bx * 32, r0 = by * 32;
#pragma unroll
  for (int i = 0; i < 32; i += 8)
    tile[ty + i][tx] = src[(size_t)(r0 + ty + i) * N_ + c0 + tx];
  __syncthreads();
#pragma unroll
  for (int i = 0; i < 32; i += 8)
    dst[(size_t)(c0 + ty + i) * 2048 + r0 + tx] = (bf16)tile[tx][ty + i];
}

// ------------------------------------------------------------- RoPE tables ---
__global__ void k_rope_inv(double* __restrict__ inv) {
  int i = threadIdx.x;
  if (i < 64) inv[i] = pow(10000.0, -(double)i / 64.0);
}

__global__ __launch_bounds__(256) void k_rope_tables(const double* __restrict__ inv,
                                                     float* __restrict__ cosT,
                                                     float* __restrict__ sinT) {
  int idx = blockIdx.x * 256 + threadIdx.x;  // S*64
  int s = idx >> 6, i = idx & 63;
  double f = (double)s * inv[i];
  double n = floor(f * 0.15915494309189535 + 0.5);
  float r = (float)(f - n * 6.283185307179586);
  cosT[idx] = cosf(r);
  sinT[idx] = sinf(r);
}

// ----------------------------------------- RoPE apply, Q and K in one grid ---
constexpr size_t NQP = (size_t)CM * CHQ * 64;                 // Q pair count
__global__ __launch_bounds__(256) void k_rope2(bf16* __restrict__ qb,
                                               bf16* __restrict__ kb,
                                               const float* __restrict__ cosT,
                                               const float* __restrict__ sinT) {
  size_t idx = (size_t)blockIdx.x * 256 + threadIdx.x;
  bf16* ptr; int s, i;
  if (idx < NQP) {
    i = (int)(idx & 63); s = (int)((idx >> 10) & (CS - 1)); ptr = qb + 2 * idx;
  } else {
    size_t j = idx - NQP;
    i = (int)(j & 63); s = (int)((j >> 6) & (CS - 1)); ptr = kb + 2 * j;
  }
  bf16x2 p = *(bf16x2*)ptr;
  float xe = (float)p[0], xo = (float)p[1];
  float c = cosT[s * 64 + i], sn = sinT[s * 64 + i];
  bf16x2 o;
  o[0] = (bf16)(xe * c - xo * sn);
  o[1] = (bf16)(xe * sn + xo * c);
  *(bf16x2*)ptr = o;
}

// --------------------------------------------- GEMM: 256x256 8-phase (T2-T5) --
// C = A[M][K] * Bt[N][K]^T. 512 thr = 8 waves (2M x 4N), wave tile 128x64,
// BK=64, double-buffered 2x64KB LDS, counted vmcnt (never 0 in steady state).
// Per K-tile: 4 quadrant phases; Q4 = {dsread, lgkmcnt(0), barrier,
// stage(t+2) -> freed buffer, MFMA, vmcnt(8), barrier}. Race-freedom: writes
// to a buffer are issued only after the barrier that follows all waves'
// completed reads of it; reads resume only after the barrier that follows
// each wave's vmcnt(8) (tile t+1's 8 loads are strictly older than t+2's 8).
constexpr int GBM = 256, GBN = 256, GBK = 64;

template <int EPI>
__global__ __launch_bounds__(512, 2)
void k_gemm8(const bf16* __restrict__ A, const bf16* __restrict__ Bt,
             void* __restrict__ Cp, bf16* __restrict__ Ck, bf16* __restrict__ Cv,
             int M, int N, int K) {
  __shared__ alignas(16) char lds[2][65536];        // [buf][A 32KB | B 32KB]
  const int tid = threadIdx.x;
  const int wave = tid >> 6, lane = tid & 63;
  const int wm = wave >> 2, wn = wave & 3;          // wave tile 128 x 64
  const int bn0 = blockIdx.x * GBN;
  const int bm0 = blockIdx.y * GBM;
  const int lr = (lane >> 4) * 4, lc = lane & 15;

  // staging: 4 rounds of 8KB per operand; LDS[r][cb] holds global byte
  // (cb ^ ((r&7)<<4)) — XOR involution on source address and on read.
  int gOff[4], ldsOff[4];
#pragma unroll
  for (int i = 0; i < 4; ++i) {
    int o = i * 8192 + tid * 16;
    int r = o >> 7;
    gOff[i] = r * (K * 2) + ((o & 127) ^ ((r & 7) << 4));
    ldsOff[i] = i * 8192 + wave * 1024;             // wave-uniform; +lane*16 HW
  }
  const char* Abase = (const char*)A + (size_t)bm0 * (K * 2);
  const char* Bbase = (const char*)Bt + (size_t)bn0 * (K * 2);

  f32x4 acc[8][4];
#pragma unroll
  for (int i = 0; i < 8; ++i)
#pragma unroll
    for (int j = 0; j < 4; ++j) acc[i][j] = (f32x4){0.f, 0.f, 0.f, 0.f};

#define STAGE8(kt_, buf_) do {                                                  \
    const char* As_ = Abase + (kt_) * 128;                                      \
    const char* Bs_ = Bbase + (kt_) * 128;                                      \
    char* dA_ = (char*)lds[buf_];                                               \
    char* dB_ = (char*)lds[buf_] + 32768;                                       \
    _Pragma("unroll")                                                           \
    for (int i_ = 0; i_ < 4; ++i_) {                                            \
      __builtin_amdgcn_global_load_lds((const AS1 void*)(As_ + gOff[i_]),       \
                                       (AS3 void*)(dA_ + ldsOff[i_]), 16, 0, 0);\
      __builtin_amdgcn_global_load_lds((const AS1 void*)(Bs_ + gOff[i_]),       \
                                       (AS3 void*)(dB_ + ldsOff[i_]), 16, 0, 0);\
    } } while (0)

#define LOAD_A(qr_) _Pragma("unroll")                                           \
    for (int st = 0; st < 4; ++st) {                                            \
      int row = wm * 128 + (qr_) * 64 + st * 16 + lc;                           \
      _Pragma("unroll")                                                         \
      for (int kk = 0; kk < 2; ++kk) {                                          \
        int cb = (kk * 64 + (lane >> 4) * 16) ^ ((row & 7) << 4);               \
        af[st][kk] = *(const s16x8*)(bufA + row * 128 + cb);                    \
      } }

#define LOAD_B(qc_) _Pragma("unroll")                                           \
    for (int st = 0; st < 2; ++st) {                                            \
      int rb = wn * 64 + (qc_) * 32 + st * 16 + lc;                             \
      _Pragma("unroll")                                                         \
      for (int kk = 0; kk < 2; ++kk) {                                          \
        int cb = (kk * 64 + (lane >> 4) * 16) ^ ((rb & 7) << 4);                \
        bfr[st][kk] = *(const s16x8*)(bufB + rb * 128 + cb);                    \
      } }

#define MFMA_Q(qr_, qc_) do {                                                   \
    __builtin_amdgcn_s_setprio(1);                                              \
    _Pragma("unroll")                                                           \
    for (int sa = 0; sa < 4; ++sa)                                              \
      _Pragma("unroll")                                                         \
      for (int sb = 0; sb < 2; ++sb)                                            \
        _Pragma("unroll")                                                       \
        for (int kk = 0; kk < 2; ++kk)                                          \
          acc[(qr_) * 4 + sa][(qc_) * 2 + sb] =                                 \
              MFMA32(af[sa][kk], bfr[sb][kk], acc[(qr_) * 4 + sa][(qc_) * 2 + sb]); \
    __builtin_amdgcn_s_setprio(0);                                              \
  } while (0)

  const int nkt = K >> 6;
  // prologue: tiles 0 and 1 in flight; tile 0 landed before first read.
  STAGE8(0, 0);
  STAGE8(1, 1);
  asm volatile("s_waitcnt vmcnt(8)" ::: "memory");
  __builtin_amdgcn_s_barrier();

  for (int kt = 0; kt < nkt; ++kt) {
    const char* bufA = (const char*)lds[kt & 1];
    const char* bufB = (const char*)lds[kt & 1] + 32768;
    s16x8 af[4][2], bfr[2][2];
    // P1: quadrant (0,0)
    LOAD_A(0);
    LOAD_B(0);
    MFMA_Q(0, 0);
    // P2: (0,1) — A reused
    LOAD_B(1);
    MFMA_Q(0, 1);
    // P3: (1,1) — B reused
    LOAD_A(1);
    MFMA_Q(1, 1);
    // P4: (1,0) — re-read B qc0; then stage + counted vmcnt
    LOAD_B(0);
    asm volatile("s_waitcnt lgkmcnt(0)" ::: "memory");  // my reads of buf done
    __builtin_amdgcn_s_barrier();                       // all waves' reads done
    if (kt + 2 < nkt) STAGE8(kt + 2, kt & 1);           // refill freed buffer
    MFMA_Q(1, 0);                                       // overlaps load issue
    if (kt + 2 < nkt) {
      asm volatile("s_waitcnt vmcnt(8)" ::: "memory");  // tile t+1 landed
    } else if (kt + 1 < nkt) {
      asm volatile("s_waitcnt vmcnt(0)" ::: "memory");  // drain for last tile
    }
    __builtin_amdgcn_s_barrier();
  }
#undef STAGE8
#undef LOAD_A
#undef LOAD_B
#undef MFMA_Q

  // epilogue. C/D frag layout: col = lane&15, row = (lane>>4)*4 + reg.
  if constexpr (EPI == 4) {
    if (bn0 < 2048) {               // Q natural: qb[m][n], stride 2048
      bf16* C = (bf16*)Cp;
#pragma unroll
      for (int i = 0; i < 8; ++i)
#pragma unroll
        for (int j = 0; j < 4; ++j) {
          int n = bn0 + wn * 64 + j * 16 + lc;
          int m = bm0 + wm * 128 + i * 16 + lr;
#pragma unroll
          for (int r = 0; r < 4; ++r)
            C[(size_t)(m + r) * 2048 + n] = (bf16)acc[i][j][r];
        }
    } else if (bn0 < 2560) {        // K: kb[b][kv][s][d]
#pragma unroll
      for (int i = 0; i < 8; ++i)
#pragma unroll
        for (int j = 0; j < 4; ++j) {
          int n = bn0 - 2048 + wn * 64 + j * 16 + lc;
          int kvh = n >> 7, d = n & 127;
          int m = bm0 + wm * 128 + i * 16 + lr;
          int b = m >> 12, s0i = m & (CS - 1);
#pragma unroll
          for (int r = 0; r < 4; ++r)
            Ck[(((size_t)b * CHKV + kvh) * CS + (s0i + r)) * CHD + d] = (bf16)acc[i][j][r];
        }
    } else {                        // V^T: vT[b][kv][d][s]
#pragma unroll
      for (int i = 0; i < 8; ++i)
#pragma unroll
        for (int j = 0; j < 4; ++j) {
          int n = bn0 - 2560 + wn * 64 + j * 16 + lc;
          int kvh = n >> 7, d = n & 127;
          int m = bm0 + wm * 128 + i * 16 + lr;
          int b = m >> 12, s0i = m & (CS - 1);
          bf16x4 pk;
          pk[0] = (bf16)acc[i][j][0]; pk[1] = (bf16)acc[i][j][1];
          pk[2] = (bf16)acc[i][j][2]; pk[3] = (bf16)acc[i][j][3];
          *(bf16x4*)(Cv + (((size_t)b * CHKV + kvh) * CHD + d) * CS + s0i) = pk;
        }
    }
  } else {                          // fp32 natural
#pragma unroll
    for (int i = 0; i < 8; ++i)
#pragma unroll
      for (int j = 0; j < 4; ++j) {
        int n = bn0 + wn * 64 + j * 16 + lc;
        int m = bm0 + wm * 128 + i * 16 + lr;
#pragma unroll
        for (int r = 0; r < 4; ++r)
          ((float*)Cp)[(size_t)(m + r) * N + n] = acc[i][j][r];
      }
  }
}

// -------------------------------------------------------------- attention ----
// (unchanged from round 7 — V pair-row swizzle, interior mask skip)
__global__ __launch_bounds__(256) void k_attn(const bf16* __restrict__ Q,
                                              const bf16* __restrict__ Kb,
                                              const bf16* __restrict__ Vt,
                                              bf16* __restrict__ O) {
  __shared__ alignas(16) char lds[2][16384];   // [buf][K 8KB | V 8KB]
  int blk = (int)blockIdx.x;
  blk = (blk & 7) * 128 + (blk >> 3);          // XCD-chunked swizzle (nwg=1024)
  const int qt = blk & 127;
  const int kv = (blk >> 7) & 3;
  const int b  = blk >> 9;
  const int tid = threadIdx.x;
  const int lane = tid & 63, wv = tid >> 6;
  const int g = lane >> 4, qi = lane & 15;
  const int h = kv * 4 + wv;
  const int q0 = qt * 32;
  const float SCL2 = 0.1275174308f;            // (1/sqrt(128)) * log2(e)

  s16x8 qf[2][4];
#pragma unroll
  for (int sub = 0; sub < 2; ++sub) {
    const bf16* qb_ = Q + (((size_t)b * CS + q0 + sub * 16 + qi) * CHQ + h) * CHD + g * 8;
#pragma unroll
    for (int t = 0; t < 4; ++t) qf[sub][t] = *(const s16x8*)(qb_ + t * 32);
  }

  f32x4 ot[2][8];
#pragma unroll
  for (int sub = 0; sub < 2; ++sub)
#pragma unroll
    for (int t = 0; t < 8; ++t) ot[sub][t] = (f32x4){0.f, 0.f, 0.f, 0.f};
  float m_run[2] = {-__builtin_inff(), -__builtin_inff()};
  float l_run[2] = {0.f, 0.f};

  const int kstart = (q0 >= CW) ? (q0 - CW) : 0;
  const int nc = (q0 + 32 - kstart) >> 5;

  const char* Kbase = (const char*)Kb + (size_t)(b * CHKV + kv) * CS * 256;
  const char* Vbase = (const char*)Vt + (size_t)(b * CHKV + kv) * CHD * (CS * 2);

  const int krow = tid >> 4;
  const int kcol = (tid & 15) * 16;
  const int ksw0 = krow * 256 + (kcol ^ ((krow & 7) << 4));
  const int ksw1 = (krow + 16) * 256 + (kcol ^ ((krow & 7) << 4));
  const int vA = tid * 16;
  const int vr0 = vA >> 7;
  const int vL = (vA & 127) ^ ((vr0 & 7) << 4);
  const size_t vsw0 = (size_t)(2 * vr0 + (vL >> 6)) * (CS * 2) + (vL & 63);
  const size_t vsw1 = vsw0 + (size_t)64 * (CS * 2);

#define STAGE(kc_, buf_) do {                                                   \
    const char* kS_ = Kbase + (size_t)(kc_) * 256;                              \
    const char* vS_ = Vbase + (size_t)(kc_) * 2;                                \
    char* d_ = (char*)lds[buf_];                                                \
    __builtin_amdgcn_global_load_lds(                                           \
        (const AS1 void*)(kS_ + ksw0),                                          \
        (AS3 void*)(d_ + wv * 1024), 16, 0, 0);                                 \
    __builtin_amdgcn_global_load_lds(                                           \
        (const AS1 void*)(kS_ + ksw1),                                          \
        (AS3 void*)(d_ + 4096 + wv * 1024), 16, 0, 0);                          \
    __builtin_amdgcn_global_load_lds(                                           \
        (const AS1 void*)(vS_ + vsw0),                                          \
        (AS3 void*)(d_ + 8192 + wv * 1024), 16, 0, 0);                          \
    __builtin_amdgcn_global_load_lds(                                           \
        (const AS1 void*)(vS_ + vsw1),                                          \
        (AS3 void*)(d_ + 12288 + wv * 1024), 16, 0, 0);                         \
  } while (0)

  STAGE(kstart, 0);
  __syncthreads();
  int cur = 0;

  for (int c = 0; c < nc; ++c) {
    const int kc = kstart + c * 32;
    if (c + 1 < nc) STAGE(kc + 32, cur ^ 1);

    const char* KL = (const char*)lds[cur];
    const char* VL = (const char*)lds[cur] + 8192;

    f32x4 sc[2][2];
    sc[0][0] = (f32x4){0.f,0.f,0.f,0.f}; sc[0][1] = (f32x4){0.f,0.f,0.f,0.f};
    sc[1][0] = (f32x4){0.f,0.f,0.f,0.f}; sc[1][1] = (f32x4){0.f,0.f,0.f,0.f};
    __builtin_amdgcn_s_setprio(1);
#pragma unroll
    for (int t = 0; t < 4; ++t) {
      const int co = (t * 64 + g * 16) ^ ((qi & 7) << 4);
      s16x8 k0 = *(const s16x8*)(KL + qi * 256 + co);
      s16x8 k1 = *(const s16x8*)(KL + 4096 + qi * 256 + co);
      sc[0][0] = MFMA32(k0, qf[0][t], sc[0][0]);
      sc[0][1] = MFMA32(k1, qf[0][t], sc[0][1]);
      sc[1][0] = MFMA32(k0, qf[1][t], sc[1][0]);
      sc[1][1] = MFMA32(k1, qf[1][t], sc[1][1]);
    }
    __builtin_amdgcn_s_setprio(0);

    const bool edge = (kc + 31 > q0) || (kc + 481 < q0);

    s16x4 pb[2][2];
#pragma unroll
    for (int sub = 0; sub < 2; ++sub) {
      const int qg = q0 + sub * 16 + qi;
      float p[8];
      if (edge) {
#pragma unroll
        for (int hf = 0; hf < 2; ++hf)
#pragma unroll
          for (int r = 0; r < 4; ++r) {
            int key = kc + hf * 16 + g * 4 + r;
            float v = sc[sub][hf][r] * SCL2;
            p[hf * 4 + r] = (key <= qg && key + CW >= qg) ? v : -__builtin_inff();
          }
      } else {
#pragma unroll
        for (int hf = 0; hf < 2; ++hf)
#pragma unroll
          for (int r = 0; r < 4; ++r)
            p[hf * 4 + r] = sc[sub][hf][r] * SCL2;
      }
      float pm = fmaxf(fmaxf(fmaxf(p[0], p[1]), fmaxf(p[2], p[3])),
                       fmaxf(fmaxf(p[4], p[5]), fmaxf(p[6], p[7])));
      pm = fmaxf(pm, __shfl_xor(pm, 16));
      pm = fmaxf(pm, __shfl_xor(pm, 32));
      if (__any(pm - m_run[sub] > 11.5f)) {     // defer-rescale (T13), base-2
        float mn = fmaxf(m_run[sub], pm);
        float fs = exp2f(m_run[sub] - mn);      // first chunk: exp2(-inf)=0
        l_run[sub] *= fs;
#pragma unroll
        for (int t = 0; t < 8; ++t) {
          ot[sub][t][0] *= fs; ot[sub][t][1] *= fs;
          ot[sub][t][2] *= fs; ot[sub][t][3] *= fs;
        }
        m_run[sub] = mn;
      }
      float rs = 0.f;
#pragma unroll
      for (int i2 = 0; i2 < 8; ++i2) { p[i2] = exp2f(p[i2] - m_run[sub]); rs += p[i2]; }
      rs += __shfl_xor(rs, 16);
      rs += __shfl_xor(rs, 32);
      l_run[sub] += rs;
#pragma unroll
      for (int j = 0; j < 4; ++j) {
        pb[sub][0][j] = __builtin_bit_cast(short, (bf16)p[j]);
        pb[sub][1][j] = __builtin_bit_cast(short, (bf16)p[4 + j]);
      }
    }

    __builtin_amdgcn_s_setprio(1);
#pragma unroll
    for (int t = 0; t < 8; ++t) {
      const int rowd = t * 16 + qi;
      const int vr_ = rowd >> 1;               // pair-row
      const int base = vr_ * 128;
      const int dsel = (rowd & 1) << 6;
      const int sw = (vr_ & 7) << 4;
      s16x4 v0 = *(const s16x4*)(VL + base + ((dsel + g * 8) ^ sw));
      s16x4 v1 = *(const s16x4*)(VL + base + ((dsel + 32 + g * 8) ^ sw));
      ot[0][t] = MFMA16(v0, pb[0][0], ot[0][t]);
      ot[0][t] = MFMA16(v1, pb[0][1], ot[0][t]);
      ot[1][t] = MFMA16(v0, pb[1][0], ot[1][t]);
      ot[1][t] = MFMA16(v1, pb[1][1], ot[1][t]);
    }
    __builtin_amdgcn_s_setprio(0);

    __syncthreads();
    cur ^= 1;
  }
#undef STAGE

#pragma unroll
  for (int sub = 0; sub < 2; ++sub) {
    float invl = 1.0f / l_run[sub];
    bf16* ob = O + (((size_t)b * CS + q0 + sub * 16 + qi) * CHQ + h) * CHD;
#pragma unroll
    for (int t = 0; t < 8; ++t) {
      bf16x4 pk;
      pk[0] = (bf16)(ot[sub][t][0] * invl);
      pk[1] = (bf16)(ot[sub][t][1] * invl);
      pk[2] = (bf16)(ot[sub][t][2] * invl);
      pk[3] = (bf16)(ot[sub][t][3] * invl);
      *(bf16x4*)(ob + t * 16 + g * 4) = pk;
    }
  }
}

// ------------------------------------------------------------------ launch ---
extern "C" void kernel_launch(void* const* d_in, const int* in_sizes, int n_in,
                              void* d_out, int out_size, void* d_ws, size_t ws_size,
                              hipStream_t stream) {
  const float* x = (const float*)d_in[0];
  const float* g = (const float*)d_in[1];
  const float* wq = (const float*)d_in[2];
  const float* wk = (const float*)d_in[3];
  const float* wv = (const float*)d_in[4];
  const float* wo = (const float*)d_in[5];
  float* out = (float*)d_out;

  char* p = (char*)d_ws;
  bf16* xn = (bf16*)p;    p += (size_t)CM * CD * 2;           // 32 MiB
  bf16* wqkvT = (bf16*)p; p += (size_t)3072 * CD * 2;         // 12 MiB
  bf16* woT = (bf16*)p;   p += (size_t)CD * CD * 2;           //  8 MiB
  double* invT = (double*)p; p += 4096;
  float* cosT = (float*)p; p += (size_t)CS * 64 * 4;          //  1 MiB
  float* sinT = (float*)p; p += (size_t)CS * 64 * 4;          //  1 MiB
  bf16* qb = (bf16*)p;  p += (size_t)CM * CD * 2;             // 32 MiB
  bf16* kb = (bf16*)p;  p += (size_t)CM * (CHKV * CHD) * 2;   //  8 MiB [b][kv][s][d]
  bf16* vT = (bf16*)p;  p += (size_t)CM * (CHKV * CHD) * 2;   //  8 MiB [b][kv][d][s]
  bf16* ao = xn;  // alias: xn dead after the QKV GEMM

  k_rope_inv<<<1, 64, 0, stream>>>(invT);
  k_rope_tables<<<(CS * 64) / 256, 256, 0, stream>>>(invT, cosT, sinT);
  k_rmsnorm<<<CM, 256, 0, stream>>>(x, g, xn);
  k_transpose_all<<<10240, 256, 0, stream>>>(wq, wk, wv, wo, wqkvT, woT);

  k_gemm8<4><<<dim3(3072 / GBN, CM / GBM), 512, 0, stream>>>(xn, wqkvT, qb, kb, vT,
                                                             CM, 3072, CD);

  k_rope2<<<(int)((NQP + (size_t)CM * CHKV * 64) / 256), 256, 0, stream>>>(qb, kb, cosT, sinT);

  k_attn<<<CB * CHKV * (CS / 32), 256, 0, stream>>>(qb, kb, vT, ao);

  k_gemm8<0><<<dim3(CD / GBN, CM / GBM), 512, 0, stream>>>(ao, woT, out, nullptr, nullptr,
                                                           CM, CD, CD);
}